// Round 2
// baseline (7824.784 us; speedup 1.0000x reference)
//
#include <hip/hip_runtime.h>

// TimeLSTM on MI355X (gfx950). B=64,S=1024,D=128,H=256.
// Scan: 64 blocks x 512 threads, 2 waves/EU (256-VGPR budget).
// ROUND-7 ROOT CAUSE (corrected): round-5's pin asm("" : "+v"(w)) lacked
// `volatile` — a non-volatile asm with outputs is a pure function, so the
// allocator rematerialized it by RE-EXECUTING the feeding WX load every
// iteration (VGPR_Count=128 proved nothing stayed live; 500 KB/step/CU L2
// stream at ~60 B/cyc/CU = 3.4 us/step matched the 3.9 us/step measured).
// Round-6's asm-volatile global_load pin crashed (untracked vmcnt / VMEM asm
// hazards). FIX: plain compiler loads + asm volatile("" : "+v"(w)) — a
// volatile asm cannot be duplicated or rematerialized, so the values must
// stay live in VGPRs; zero instructions emitted, loads stay cached+tracked.
// Partition per thread (80 chunks): 44 pinned VGPR (176 regs: rowA 0..31 +
// rowB 0..11) + 19 LDS (slots 44..62, 159.7 KB dynamic) + 17 streamed from
// L2 (slots 63..79 = rowB 31 + W_d 0..15, 136 KB/step/CU, 4-deep pipeline).

#define B_ 64
#define S_ 1024
#define D_ 128
#define H_ 256
#define FH_ 1024
#define SMEM_BYTES (4096 + 19 * 512 * 16)   // 159744 <= 160 KiB

typedef _Float16 half2_t __attribute__((ext_vector_type(2)));
typedef _Float16 half4_t __attribute__((ext_vector_type(4)));
typedef _Float16 half8_t __attribute__((ext_vector_type(8)));
typedef float    f32x4   __attribute__((ext_vector_type(4)));

union HW { half8_t v; half2_t p[4]; };

__device__ inline float dot2acc(half2_t a, half2_t b, float c) {
#if __has_builtin(__builtin_amdgcn_fdot2)
    return __builtin_amdgcn_fdot2(a, b, c, false);
#else
    return c + (float)a[0] * (float)b[0] + (float)a[1] * (float)b[1];
#endif
}

__device__ inline float dot8acc(half8_t a, half8_t b, float c) {
    HW ua; ua.v = a;
    HW ub; ub.v = b;
    c = dot2acc(ua.p[0], ub.p[0], c);
    c = dot2acc(ua.p[1], ub.p[1], c);
    c = dot2acc(ua.p[2], ub.p[2], c);
    c = dot2acc(ua.p[3], ub.p[3], c);
    return c;
}

__device__ inline float sigmoid_f(float x) { return 1.f / (1.f + __expf(-x)); }
__device__ inline float tanh_f(float x)    { return 1.f - 2.f / (__expf(2.f * x) + 1.f); }

// ---------------------------------------------------------------------------
// Pack (unchanged, validated). WX slot-major: WX[slot][512][8], slot in [0,80):
//   slot<32 : rowA chunks (f for t<256, o for t>=256)
//   32..63  : rowB chunks (i / c~)
//   64..79  : W_d[e] chunk (slot-64) + hi*16  (cols 0..127 / 128..255)
// ---------------------------------------------------------------------------
__global__ __launch_bounds__(256) void pack_kernel(
    const float* __restrict__ Wall, const float* __restrict__ Wd,
    const float* __restrict__ Uall, const float* __restrict__ ts,
    _Float16* __restrict__ WX, _Float16* __restrict__ U16,
    float* __restrict__ decay)
{
    int idx = blockIdx.x * 256 + threadIdx.x;
    if (idx < 40960) {
        int slot = idx >> 9, t = idx & 511;
        int e = t & 255, hi = t >> 8;
        int row, ch;
        if (slot < 32)      { row = (hi ? 512 : 0)   + e; ch = slot; }
        else if (slot < 64) { row = (hi ? 768 : 256) + e; ch = slot - 32; }
        else                { row = 1024 + e;             ch = (slot - 64) + (hi ? 16 : 0); }
        const float* src = (row < 1024) ? (Wall + (size_t)row * H_ + ch * 8)
                                        : (Wd + (size_t)(row - 1024) * H_ + ch * 8);
        _Float16* dst = WX + ((size_t)slot * 512 + t) * 8;
        #pragma unroll
        for (int j = 0; j < 8; j++) dst[j] = (_Float16)src[j];
    } else if (idx < 40960 + 131072) {
        int i = idx - 40960;
        U16[i] = (_Float16)Uall[i];
    } else if (idx < 40960 + 131072 + 65536) {
        int i = idx - 172032;
        int bb = i >> 10, s = i & 1023;
        float d = 1.f;
        if (s > 0) {
            float dt = ts[bb * S_ + s] - ts[bb * S_ + s - 1];
            dt = fmaxf(dt, 1e-6f);
            d = 1.f / logf(2.718281828459045f + dt);
        }
        decay[i] = d;
    }
}

// ---------------------------------------------------------------------------
// u GEMM via MFMA 16x16x32 f16 (unchanged, validated). Stores u
// gate-interleaved: u16[row][e*4+g], g in {f,i,o,c~}.
// ---------------------------------------------------------------------------
__global__ __launch_bounds__(256) void u_gemm_mfma(
    const float* __restrict__ x, const _Float16* __restrict__ U16,
    const float* __restrict__ Ub, _Float16* __restrict__ u16)
{
    int wave = threadIdx.x >> 6, lane = threadIdx.x & 63;
    size_t row0 = (size_t)blockIdx.x * 64 + wave * 16;
    int n0 = blockIdx.y * 256;
    int am = lane & 15;
    int ak = (lane >> 4) * 8;
    const float* xr = x + (row0 + am) * D_ + ak;

    f32x4 acc[16];
    #pragma unroll
    for (int nt = 0; nt < 16; nt++) acc[nt] = (f32x4){0.f, 0.f, 0.f, 0.f};

    #pragma unroll
    for (int kc = 0; kc < 4; kc++) {
        half8_t a;
        #pragma unroll
        for (int e = 0; e < 8; e++) a[e] = (_Float16)xr[kc * 32 + e];
        #pragma unroll
        for (int nt = 0; nt < 16; nt++) {
            half8_t bfr = *(const half8_t*)(U16 + (size_t)(n0 + nt * 16 + am) * D_ + kc * 32 + ak);
            acc[nt] = __builtin_amdgcn_mfma_f32_16x16x32_f16(a, bfr, acc[nt], 0, 0, 0);
        }
    }

    int cr = (lane >> 4) * 4;
    #pragma unroll
    for (int nt = 0; nt < 16; nt++) {
        int col = n0 + nt * 16 + am;
        float bias = Ub[col];
        int e = col & 255, g = col >> 8;
        #pragma unroll
        for (int i = 0; i < 4; i++) {
            u16[(row0 + cr + i) * (size_t)FH_ + e * 4 + g] = (_Float16)(acc[nt][i] + bias);
        }
    }
}

// ---------------------------------------------------------------------------
// Scan.
// ---------------------------------------------------------------------------
__global__ void __launch_bounds__(512) __attribute__((amdgpu_waves_per_eu(2, 2)))
scan_kernel(
    const _Float16* __restrict__ u16, const _Float16* __restrict__ WX,
    const float* __restrict__ Wb, const float* __restrict__ Wdb,
    const float* __restrict__ decay, float* __restrict__ out)
{
    int b = blockIdx.x, t = threadIdx.x;
    int e = t & 255, hi = t >> 8;

    extern __shared__ __align__(16) char smem[];
    _Float16* h16  = (_Float16*)smem;                 // 512 B
    _Float16* c16  = (_Float16*)(smem + 512);         // 512 B
    float*    po_s = (float*)(smem + 1024);           // 1 KB
    float*    pc_s = (float*)(smem + 2048);           // 1 KB
    float*    adh_s= (float*)(smem + 3072);           // 1 KB
    half8_t*  wl   = (half8_t*)(smem + 4096);         // 19 chunks x 512 thr

    const half8_t* __restrict__ WX8 = (const half8_t*)WX;

    // ---- LDS weights: slots 44..62 (rowB chunks 12..30) ----
    #pragma unroll
    for (int j = 0; j < 19; j++) wl[(size_t)j * 512 + t] = WX8[(size_t)(44 + j) * 512 + t];

    // ---- pinned weights: slots 0..43 (rowA 0..31 + rowB 0..11) ----
    half8_t wA[32], wB[12];
    #pragma unroll
    for (int cc = 0; cc < 32; cc++) wA[cc] = WX8[(size_t)cc * 512 + t];
    #pragma unroll
    for (int j = 0; j < 12; j++)  wB[j] = WX8[(size_t)(32 + j) * 512 + t];

    // ---- PIN: VOLATILE empty asm. A volatile asm cannot be duplicated or
    //      rematerialized (unlike round-5's non-volatile version, which the
    //      allocator re-executed — reload included — every iteration). The
    //      values therefore stay live in VGPRs across the in-loop barriers. ----
    #pragma unroll
    for (int cc = 0; cc < 32; cc++) asm volatile("" : "+v"(wA[cc]));
    #pragma unroll
    for (int j = 0; j < 12; j++)  asm volatile("" : "+v"(wB[j]));

    float bA = Wb[hi * 512 + e];           // f / o bias
    float bB = Wb[hi * 512 + 256 + e];     // i / c~ bias
    float wdbt = Wdb[e];

    if (hi == 0) { h16[e] = (_Float16)0.f; c16[e] = (_Float16)0.f; }
    float c_reg = 0.f, hn = 0.f;
    __syncthreads();

    const _Float16* __restrict__ ub   = u16 + (size_t)b * S_ * FH_;
    const float*    __restrict__ db   = decay + (size_t)b * S_;
    float*          __restrict__ outb = out + (size_t)b * S_ * H_;
    // streamed slots 63..79: rowB chunk 31 (1) + W_d chunks 0..15 (16)
    const half8_t*  __restrict__ sp   = WX8 + (size_t)63 * 512 + t;

    const half8_t* hb8 = (const half8_t*)h16;
    const half8_t* cb8 = (const half8_t*)c16 + hi * 16;

    for (int s = 0; s < S_; s++) {
        half2_t u2 = *(const half2_t*)(ub + (size_t)s * FH_ + e * 4 + hi * 2);

        // rolling 4-deep stream pipeline over 17 chunks
        half8_t sw[4];
        #pragma unroll
        for (int j = 0; j < 4; j++) sw[j] = sp[(size_t)j * 512];

        float aA = 0.f, aB = 0.f, aD = 0.f;

        // pinned-register dots (rowA 0..11 + rowB 0..11)
        #pragma unroll
        for (int cc = 0; cc < 12; cc++) {
            half8_t h8 = hb8[cc];
            aA = dot8acc(h8, wA[cc], aA);
            aB = dot8acc(h8, wB[cc], aB);
        }
        // rowA 12..30 + rowB(LDS) 12..30
        #pragma unroll
        for (int cc = 12; cc < 31; cc++) {
            half8_t h8 = hb8[cc];
            aA = dot8acc(h8, wA[cc], aA);
            aB = dot8acc(h8, wl[(size_t)(cc - 12) * 512 + t], aB);
        }
        // rowA chunk 31 (pinned); keep h31 for the streamed rowB-31 dot
        half8_t h31 = hb8[31];
        aA = dot8acc(h31, wA[31], aA);

        // streamed: rowB 31 (with h), then W_d 0..15 (with c)
        #pragma unroll
        for (int i = 0; i < 17; i++) {
            half8_t w = sw[i & 3];
            if (i + 4 < 17) sw[i & 3] = sp[(size_t)(i + 4) * 512];
            if (i == 0) aB = dot8acc(h31, w, aB);
            else        aD = dot8acc(cb8[i - 1], w, aD);
        }

        float pA = aA + bA + (float)u2[0];
        float pB = aB + bB + (float)u2[1];

        if (hi) {
            po_s[e]  = pA;
            pc_s[e]  = pB;
            adh_s[e] = aD;
        }
        __syncthreads();
        if (!hi) {
            float dly  = db[s];
            float cs   = tanh_f(aD + adh_s[e] + wdbt);
            float cadj = (c_reg - cs) + cs * dly;
            float cn   = sigmoid_f(pA) * cadj + sigmoid_f(pB) * tanh_f(pc_s[e]);
            hn = sigmoid_f(po_s[e]) * tanh_f(cn);
            c_reg = cn;
            outb[(size_t)s * H_ + e] = hn;
            h16[e] = (_Float16)hn;
            c16[e] = (_Float16)cn;
        }
        __syncthreads();
    }

    if (!hi) {
        out[(size_t)B_ * S_ * H_ + (size_t)b * H_ + e] = hn;
        out[(size_t)B_ * S_ * H_ + (size_t)B_ * H_ + (size_t)b * H_ + e] = c_reg;
    }
}

// ---------------------------------------------------------------------------
extern "C" void kernel_launch(void* const* d_in, const int* in_sizes, int n_in,
                              void* d_out, int out_size, void* d_ws, size_t ws_size,
                              hipStream_t stream) {
    const float* inputs     = (const float*)d_in[0];   // [B,S,D]
    const float* timestamps = (const float*)d_in[1];   // [B,S]
    const float* W_all_w    = (const float*)d_in[2];   // [4H,H]
    const float* W_all_b    = (const float*)d_in[3];   // [4H]
    const float* U_all_w    = (const float*)d_in[4];   // [4H,D]
    const float* U_all_b    = (const float*)d_in[5];   // [4H]
    const float* W_d_w      = (const float*)d_in[6];   // [H,H]
    const float* W_d_b      = (const float*)d_in[7];   // [H]
    float* out = (float*)d_out;

    char* p = (char*)d_ws;
    _Float16* u16 = (_Float16*)p;   p += (size_t)B_ * S_ * FH_ * 2;   // 128 MiB
    _Float16* WX  = (_Float16*)p;   p += (size_t)80 * 512 * 8 * 2;    // 640 KiB
    _Float16* U16 = (_Float16*)p;   p += (size_t)FH_ * D_ * 2;        // 256 KiB
    float*    dec = (float*)p;                                         // 256 KiB

    (void)hipFuncSetAttribute((const void*)scan_kernel,
                              hipFuncAttributeMaxDynamicSharedMemorySize,
                              SMEM_BYTES);

    pack_kernel<<<dim3(928), dim3(256), 0, stream>>>(
        W_all_w, W_d_w, U_all_w, timestamps, WX, U16, dec);
    u_gemm_mfma<<<dim3(1024, 4), dim3(256), 0, stream>>>(
        inputs, U16, U_all_b, u16);
    scan_kernel<<<dim3(B_), dim3(512), SMEM_BYTES, stream>>>(
        u16, WX, W_all_b, W_d_b, dec, out);
}